// Round 7
// baseline (185.199 us; speedup 1.0000x reference)
//
#include <hip/hip_runtime.h>

// pred_vol shape (1,1,64,512,512) fp32; threshold 0.5; window 9 (R=4).
// Identity: thr is monotone and the window contains the center, so
// reference output == (c > 0.5 && c == max9x9x9_raw(x)) ? c : 0.
static constexpr int Dd = 64;
static constexpr int Hh = 512;
static constexpr int Ww = 512;
static constexpr int RAD = 4;
static constexpr float THRESH_V = 0.5f;
static constexpr int W4 = Ww / 4;          // 128 float4 per row
static constexpr int PLANE4 = Hh * W4;     // 65536 float4 per D-plane

static constexpr int TH = 4;               // output h-rows per block
static constexpr int DC = 16;              // output d-planes per block
static constexpr int ROWS = TH + 2 * RAD;  // 12 staged rows per plane
static constexpr int STEPS = DC + 2 * RAD; // 24 d-steps per block (FULLY UNROLLED)
static constexpr int NBLK = (Hh / TH) * (Dd / DC);  // 512 blocks

typedef float nf4 __attribute__((ext_vector_type(4)));  // native vec for nt-store

__device__ __forceinline__ float4 f4max(float4 a, float4 b) {
    return make_float4(fmaxf(a.x, b.x), fmaxf(a.y, b.y), fmaxf(a.z, b.z), fmaxf(a.w, b.w));
}
__device__ __forceinline__ int iclamp(int v, int lo, int hi) {
    return v < lo ? lo : (v > hi ? hi : v);
}

__global__ __launch_bounds__(512, 4)
void fused_nms_k(const float4* __restrict__ x4, float4* __restrict__ o4) {
    // double-buffered staging of per-plane W-max rows: 2 * 12 * 128 * 16B = 48 KB
    __shared__ float4 buf[2][ROWS * W4];

    const int tid = threadIdx.x;
    const int w4  = tid & (W4 - 1);              // 0..127
    const int hr  = tid >> 7;                    // 0..3
    const int ht  = blockIdx.x & (Hh / TH - 1);  // 0..127
    const int dc  = blockIdx.x >> 7;             // 0..3
    const int h0  = ht * TH;
    const int d0  = dc * DC;

    const int colm = w4 ? w4 - 1 : 0;
    const int colp = (w4 < W4 - 1) ? w4 + 1 : W4 - 1;

    // 9 per-thread element offsets within a plane (row + clamped col folded).
    int off[9];
#pragma unroll
    for (int k = 0; k < 3; ++k) {
        int gh = iclamp(h0 - RAD + hr + 4 * k, 0, Hh - 1);
        off[3 * k]     = gh * W4 + colm;
        off[3 * k + 1] = gh * W4 + w4;
        off[3 * k + 2] = gh * W4 + colp;
    }
    const int outrow = (h0 + hr) * W4 + w4;

    const float4 z = make_float4(0.f, 0.f, 0.f, 0.f);
    float4 ring[9], xr[5];
#pragma unroll
    for (int i = 0; i < 9; ++i) ring[i] = z;
#pragma unroll
    for (int i = 0; i < 5; ++i) xr[i] = z;

    // Preload bank for the first plane (gd uniform per block -> SGPR base).
    float4 L[9];
    {
        const float4* pl = x4 + (size_t)iclamp(d0 - RAD, 0, Dd - 1) * PLANE4;
#pragma unroll
        for (int i = 0; i < 9; ++i) L[i] = pl[off[i]];
    }

#pragma unroll
    for (int t = 0; t < STEPS; ++t) {
        float4* B = buf[t & 1];
        const float4 center = L[4];   // raw x at (gd(t), h0+hr, w4)

        // W-max of the 3 staged rows from the preloaded bank -> LDS
#pragma unroll
        for (int k = 0; k < 3; ++k) {
            float4 v0 = L[3 * k], v1 = L[3 * k + 1], v2 = L[3 * k + 2];
            float l3 = v0.w, l2 = fmaxf(v0.z, l3), l1 = fmaxf(v0.y, l2), l0 = fmaxf(v0.x, l1);
            float core = fmaxf(fmaxf(v1.x, v1.y), fmaxf(v1.z, v1.w));
            float r8 = v2.x, r9 = fmaxf(r8, v2.y), r10 = fmaxf(r9, v2.z), r11 = fmaxf(r10, v2.w);
            float4 o;
            o.x = fmaxf(l0, fmaxf(core, r8));
            o.y = fmaxf(l1, fmaxf(core, r9));
            o.z = fmaxf(l2, fmaxf(core, r10));
            o.w = fmaxf(l3, fmaxf(core, r11));
            B[k * 512 + tid] = o;
        }
        __syncthreads();

        // Prefetch plane t+1 AFTER the barrier; consumed next (unrolled) iter,
        // so the loads fly during the H/D phase below. SSA under full unroll.
        if (t + 1 < STEPS) {
            const int gd = iclamp(d0 - RAD + t + 1, 0, Dd - 1);
            const float4* pl = x4 + (size_t)gd * PLANE4;
#pragma unroll
            for (int i = 0; i < 9; ++i) L[i] = pl[off[i]];
        }

        // H-max over 9 staged rows at this thread's column (immediate offsets)
        float4 m = B[hr * W4 + w4];
#pragma unroll
        for (int i = 1; i < 9; ++i) m = f4max(m, B[(hr + i) * W4 + w4]);

        // push D-ring and center lag ring — pure renaming under full unroll
#pragma unroll
        for (int i = 0; i < 8; ++i) ring[i] = ring[i + 1];
        ring[8] = m;
#pragma unroll
        for (int i = 0; i < 4; ++i) xr[i] = xr[i + 1];
        xr[4] = center;

        if (t >= 2 * RAD) {           // ring holds planes d-4..d+4 (clamped)
            const int d = d0 + t - 2 * RAD;
            float4 mm = ring[0];
#pragma unroll
            for (int i = 1; i < 9; ++i) mm = f4max(mm, ring[i]);
            const float4 c = xr[0];   // raw center at plane d (lag 4)
            nf4 q;
            q.x = (c.x > THRESH_V && c.x == mm.x) ? c.x : 0.0f;
            q.y = (c.y > THRESH_V && c.y == mm.y) ? c.y : 0.0f;
            q.z = (c.z > THRESH_V && c.z == mm.z) ? c.z : 0.0f;
            q.w = (c.w > THRESH_V && c.w == mm.w) ? c.w : 0.0f;
            // write-once stream: bypass caches so x stays resident
            __builtin_nontemporal_store(q, (nf4*)&o4[(size_t)d * PLANE4 + outrow]);
        }
    }
}

extern "C" void kernel_launch(void* const* d_in, const int* in_sizes, int n_in,
                              void* d_out, int out_size, void* d_ws, size_t ws_size,
                              hipStream_t stream) {
    const float4* x4 = (const float4*)d_in[0];
    float4* out4 = (float4*)d_out;
    (void)d_ws; (void)ws_size; (void)in_sizes; (void)n_in; (void)out_size;
    fused_nms_k<<<dim3(NBLK), dim3(512), 0, stream>>>(x4, out4);
}

// Round 8
// 154.868 us; speedup vs baseline: 1.1959x; 1.1959x over previous
//
#include <hip/hip_runtime.h>

// pred_vol shape (1,1,64,512,512) fp32; threshold 0.5; window 9 (R=4).
// Identity: thr is monotone and the window contains the center, so
// reference output == (c > 0.5 && c == max9x9x9_raw(x)) ? c : 0.
static constexpr int Dd = 64;
static constexpr int Hh = 512;
static constexpr int Ww = 512;
static constexpr int RAD = 4;
static constexpr float THRESH_V = 0.5f;
static constexpr int W4 = Ww / 4;          // 128 float4 per row
static constexpr int PLANE4 = Hh * W4;     // 65536 float4 per D-plane

static constexpr int TH = 4;               // output h-rows per block
static constexpr int DC = 16;              // output d-planes per block
static constexpr int ROWS = TH + 2 * RAD;  // 12 staged rows per plane
static constexpr int STEPS = DC + 2 * RAD; // 24 d-steps per block
static constexpr int NBLK = (Hh / TH) * (Dd / DC);  // 512 blocks (all co-resident)

__device__ __forceinline__ float4 f4max(float4 a, float4 b) {
    return make_float4(fmaxf(a.x, b.x), fmaxf(a.y, b.y), fmaxf(a.z, b.z), fmaxf(a.w, b.w));
}
__device__ __forceinline__ int iclamp(int v, int lo, int hi) {
    return v < lo ? lo : (v > hi ? hi : v);
}

__global__ __launch_bounds__(512, 4)
void fused_nms_k(const float4* __restrict__ x4, float4* __restrict__ o4) {
    // double-buffered staging of per-plane W-max rows: 2 * 12 * 128 * 16B = 48 KB
    __shared__ float4 buf[2][ROWS * W4];

    const int tid = threadIdx.x;
    const int w4  = tid & (W4 - 1);              // 0..127
    const int hr  = tid >> 7;                    // 0..3
    // XCD swizzle: band = blockIdx&7 -> h-band of 64 rows stays on one XCD's L2
    const int b    = blockIdx.x;
    const int band = b & 7;
    const int rest = b >> 3;                     // 0..63
    const int ht   = band * 16 + (rest & 15);    // 0..127
    const int dc   = rest >> 4;                  // 0..3
    const int h0   = ht * TH;
    const int d0   = dc * DC;

    const int colm = w4 ? w4 - 1 : 0;
    const int colp = (w4 < W4 - 1) ? w4 + 1 : W4 - 1;

    // 9 per-thread element offsets within a plane (row + clamped col folded).
    int off[9];
#pragma unroll
    for (int k = 0; k < 3; ++k) {
        int gh = iclamp(h0 - RAD + hr + 4 * k, 0, Hh - 1);
        off[3 * k]     = gh * W4 + colm;
        off[3 * k + 1] = gh * W4 + w4;
        off[3 * k + 2] = gh * W4 + colp;
    }
    const int outrow = (h0 + hr) * W4 + w4;

    // Slot ring: R[t % 8] holds H-max of plane t, overwritten AFTER use.
    // Window-9 D-max at step t = max(R[0..7] (planes t-8..t-1), current m).
    float4 R[8];
    float4 L[9];
    {   // preload plane for t=0
        const float4* pl = x4 + (size_t)iclamp(d0 - RAD, 0, Dd - 1) * PLANE4;
#pragma unroll
        for (int i = 0; i < 9; ++i) L[i] = pl[off[i]];
    }

    // One d-step. slot/par/emit are compile-time at every call site.
    auto body = [&](int t, int slot, int par, bool emit) {
        float4* B = buf[par];
        // W-max of the 3 staged rows from the preloaded bank -> LDS
#pragma unroll
        for (int k = 0; k < 3; ++k) {
            float4 v0 = L[3 * k], v1 = L[3 * k + 1], v2 = L[3 * k + 2];
            float l3 = v0.w, l2 = fmaxf(v0.z, l3), l1 = fmaxf(v0.y, l2), l0 = fmaxf(v0.x, l1);
            float core = fmaxf(fmaxf(v1.x, v1.y), fmaxf(v1.z, v1.w));
            float r8 = v2.x, r9 = fmaxf(r8, v2.y), r10 = fmaxf(r9, v2.z), r11 = fmaxf(r10, v2.w);
            float4 o;
            o.x = fmaxf(l0, fmaxf(core, r8));
            o.y = fmaxf(l1, fmaxf(core, r9));
            o.z = fmaxf(l2, fmaxf(core, r10));
            o.w = fmaxf(l3, fmaxf(core, r11));
            B[k * 512 + tid] = o;
        }
        __syncthreads();

        // After the barrier (which drains vmcnt anyway): issue center reload
        // for this step's output and the plane-(t+1) prefetch; both fly
        // during the H/D phase below.
        float4 cen;
        if (emit) cen = x4[(size_t)(d0 + t - 2 * RAD) * PLANE4 + outrow];
        {
            const int gd = iclamp(d0 - RAD + t + 1, 0, Dd - 1);
            const float4* pl = x4 + (size_t)gd * PLANE4;
#pragma unroll
            for (int i = 0; i < 9; ++i) L[i] = pl[off[i]];
        }

        // H-max over 9 staged rows at this thread's column (immediate offsets)
        const float4* Bb = B + hr * W4 + w4;
        float4 m = Bb[0];
#pragma unroll
        for (int i = 1; i < 9; ++i) m = f4max(m, Bb[i * W4]);

        if (emit) {
            float4 mm = m;
#pragma unroll
            for (int i = 0; i < 8; ++i) mm = f4max(mm, R[i]);
            float4 q;
            q.x = (cen.x > THRESH_V && cen.x == mm.x) ? cen.x : 0.0f;
            q.y = (cen.y > THRESH_V && cen.y == mm.y) ? cen.y : 0.0f;
            q.z = (cen.z > THRESH_V && cen.z == mm.z) ? cen.z : 0.0f;
            q.w = (cen.w > THRESH_V && cen.w == mm.w) ? cen.w : 0.0f;
            o4[(size_t)(d0 + t - 2 * RAD) * PLANE4 + outrow] = q;
        }
        R[slot] = m;   // overwrite after use
    };

    // Prologue: fill ring with planes d0-4 .. d0+3 (clamped), no outputs.
#pragma unroll
    for (int t = 0; t < 8; ++t) body(t, t, t & 1, false);
    // Main: 16 emitting steps, unroll 8 so slot indices are static.
    for (int tb = 8; tb < STEPS; tb += 8) {
#pragma unroll
        for (int j = 0; j < 8; ++j) body(tb + j, j, j & 1, true);
    }
}

extern "C" void kernel_launch(void* const* d_in, const int* in_sizes, int n_in,
                              void* d_out, int out_size, void* d_ws, size_t ws_size,
                              hipStream_t stream) {
    const float4* x4 = (const float4*)d_in[0];
    float4* out4 = (float4*)d_out;
    (void)d_ws; (void)ws_size; (void)in_sizes; (void)n_in; (void)out_size;
    fused_nms_k<<<dim3(NBLK), dim3(512), 0, stream>>>(x4, out4);
}

// Round 9
// 139.043 us; speedup vs baseline: 1.3320x; 1.1138x over previous
//
#include <hip/hip_runtime.h>

// pred_vol shape (1,1,64,512,512) fp32; threshold 0.5; window 9 (R=4).
// Identity: thr is monotone and the window contains the center, so
// reference output == (c > 0.5 && c == max9x9x9_raw(x)) ? c : 0.
static constexpr int Dd = 64;
static constexpr int Hh = 512;
static constexpr int Ww = 512;
static constexpr int RAD = 4;
static constexpr float THRESH_V = 0.5f;
static constexpr int W4 = Ww / 4;          // 128 float4 per row
static constexpr int PLANE4 = Hh * W4;     // 65536 float4 per D-plane

static constexpr int TH = 4;               // output h-rows per block
static constexpr int DC = 16;              // output d-planes per block
static constexpr int ROWS = TH + 2 * RAD;  // 12 staged rows per plane
static constexpr int STEPS = DC + 2 * RAD; // 24 d-steps per block
static constexpr int NBLK = (Hh / TH) * (Dd / DC);  // 512 blocks (2/CU, co-resident)

typedef float nf4 __attribute__((ext_vector_type(4)));  // native vec for nt-store

__device__ __forceinline__ float4 f4max(float4 a, float4 b) {
    return make_float4(fmaxf(a.x, b.x), fmaxf(a.y, b.y), fmaxf(a.z, b.z), fmaxf(a.w, b.w));
}
__device__ __forceinline__ int iclamp(int v, int lo, int hi) {
    return v < lo ? lo : (v > hi ? hi : v);
}

// launch_bounds (512, 2): 2 blocks/CU -> 16 waves/CU -> 4 waves/SIMD -> 128 VGPR cap.
// (512, 4) capped VGPRs at 64 and spilled 27 dwords/thread (r8: WRITE 91 MB).
__global__ __launch_bounds__(512, 2)
void fused_nms_k(const float4* __restrict__ x4, float4* __restrict__ o4) {
    // double-buffered staging of per-plane W-max rows: 2 * 12 * 128 * 16B = 48 KB
    __shared__ float4 buf[2][ROWS * W4];

    const int tid = threadIdx.x;
    const int w4  = tid & (W4 - 1);              // 0..127
    const int hr  = tid >> 7;                    // 0..3
    // XCD swizzle: band = blockIdx&7 -> h-band of 64 rows stays on one XCD's L2
    const int b    = blockIdx.x;
    const int band = b & 7;
    const int rest = b >> 3;                     // 0..63
    const int ht   = band * 16 + (rest & 15);    // 0..127
    const int dc   = rest >> 4;                  // 0..3
    const int h0   = ht * TH;
    const int d0   = dc * DC;

    const int colm = w4 ? w4 - 1 : 0;
    const int colp = (w4 < W4 - 1) ? w4 + 1 : W4 - 1;

    // 9 per-thread element offsets within a plane (row + clamped col folded).
    int off[9];
#pragma unroll
    for (int k = 0; k < 3; ++k) {
        int gh = iclamp(h0 - RAD + hr + 4 * k, 0, Hh - 1);
        off[3 * k]     = gh * W4 + colm;
        off[3 * k + 1] = gh * W4 + w4;
        off[3 * k + 2] = gh * W4 + colp;
    }
    const int outrow = (h0 + hr) * W4 + w4;

    // Slot ring: R[t % 8] holds H-max of plane t, overwritten AFTER use.
    // Window-9 D-max at step t = max(R[0..7] (planes t-8..t-1), current m).
    float4 R[8];
    float4 L[9];
    {   // preload plane for t=0
        const float4* pl = x4 + (size_t)iclamp(d0 - RAD, 0, Dd - 1) * PLANE4;
#pragma unroll
        for (int i = 0; i < 9; ++i) L[i] = pl[off[i]];
    }

    // One d-step. slot/par/emit are compile-time at every call site.
    auto body = [&](int t, int slot, int par, bool emit) {
        float4* B = buf[par];
        // W-max of the 3 staged rows from the preloaded bank -> LDS
#pragma unroll
        for (int k = 0; k < 3; ++k) {
            float4 v0 = L[3 * k], v1 = L[3 * k + 1], v2 = L[3 * k + 2];
            float l3 = v0.w, l2 = fmaxf(v0.z, l3), l1 = fmaxf(v0.y, l2), l0 = fmaxf(v0.x, l1);
            float core = fmaxf(fmaxf(v1.x, v1.y), fmaxf(v1.z, v1.w));
            float r8 = v2.x, r9 = fmaxf(r8, v2.y), r10 = fmaxf(r9, v2.z), r11 = fmaxf(r10, v2.w);
            float4 o;
            o.x = fmaxf(l0, fmaxf(core, r8));
            o.y = fmaxf(l1, fmaxf(core, r9));
            o.z = fmaxf(l2, fmaxf(core, r10));
            o.w = fmaxf(l3, fmaxf(core, r11));
            B[k * 512 + tid] = o;
        }
        __syncthreads();

        // After the barrier (which drains vmcnt anyway): issue center reload
        // for this step's output and the plane-(t+1) prefetch; both fly
        // during the H/D phase below.
        float4 cen;
        if (emit) cen = x4[(size_t)(d0 + t - 2 * RAD) * PLANE4 + outrow];
        {
            const int gd = iclamp(d0 - RAD + t + 1, 0, Dd - 1);
            const float4* pl = x4 + (size_t)gd * PLANE4;
#pragma unroll
            for (int i = 0; i < 9; ++i) L[i] = pl[off[i]];
        }

        // H-max over 9 staged rows at this thread's column (immediate offsets)
        const float4* Bb = B + hr * W4 + w4;
        float4 m = Bb[0];
#pragma unroll
        for (int i = 1; i < 9; ++i) m = f4max(m, Bb[i * W4]);

        if (emit) {
            float4 mm = m;
#pragma unroll
            for (int i = 0; i < 8; ++i) mm = f4max(mm, R[i]);
            nf4 q;
            q.x = (cen.x > THRESH_V && cen.x == mm.x) ? cen.x : 0.0f;
            q.y = (cen.y > THRESH_V && cen.y == mm.y) ? cen.y : 0.0f;
            q.z = (cen.z > THRESH_V && cen.z == mm.z) ? cen.z : 0.0f;
            q.w = (cen.w > THRESH_V && cen.w == mm.w) ? cen.w : 0.0f;
            // write-once stream: don't evict the swizzled x slabs from L2
            __builtin_nontemporal_store(
                q, (nf4*)&o4[(size_t)(d0 + t - 2 * RAD) * PLANE4 + outrow]);
        }
        R[slot] = m;   // overwrite after use
    };

    // Prologue: fill ring with planes d0-4 .. d0+3 (clamped), no outputs.
#pragma unroll
    for (int t = 0; t < 8; ++t) body(t, t, t & 1, false);
    // Main: 16 emitting steps, unroll 8 so slot indices are static.
    for (int tb = 8; tb < STEPS; tb += 8) {
#pragma unroll
        for (int j = 0; j < 8; ++j) body(tb + j, j, j & 1, true);
    }
}

extern "C" void kernel_launch(void* const* d_in, const int* in_sizes, int n_in,
                              void* d_out, int out_size, void* d_ws, size_t ws_size,
                              hipStream_t stream) {
    const float4* x4 = (const float4*)d_in[0];
    float4* out4 = (float4*)d_out;
    (void)d_ws; (void)ws_size; (void)in_sizes; (void)n_in; (void)out_size;
    fused_nms_k<<<dim3(NBLK), dim3(512), 0, stream>>>(x4, out4);
}

// Round 10
// 128.726 us; speedup vs baseline: 1.4387x; 1.0801x over previous
//
#include <hip/hip_runtime.h>

// pred_vol shape (1,1,64,512,512) fp32; threshold 0.5; window 9 (R=4).
// Identity: thr is monotone and the window contains the center, so
// reference output == (c > 0.5 && c == max9x9x9_raw(x)) ? c : 0.
static constexpr int Dd = 64;
static constexpr int Hh = 512;
static constexpr int Ww = 512;
static constexpr int RAD = 4;
static constexpr float THRESH_V = 0.5f;
static constexpr int W4 = Ww / 4;          // 128 float4 per row
static constexpr int PLANE4 = Hh * W4;     // 65536 float4 per D-plane

static constexpr int TH = 4;               // output h-rows per block
static constexpr int DC = 16;              // output d-planes per block
static constexpr int ROWS = TH + 2 * RAD;  // 12 staged rows per plane
static constexpr int STEPS = DC + 2 * RAD; // 24 d-steps per block
static constexpr int NBLK = (Hh / TH) * (Dd / DC);  // 512 blocks (2/CU, co-resident)

typedef float nf4 __attribute__((ext_vector_type(4)));  // native vec for nt-store

__device__ __forceinline__ float4 f4max(float4 a, float4 b) {
    return make_float4(fmaxf(a.x, b.x), fmaxf(a.y, b.y), fmaxf(a.z, b.z), fmaxf(a.w, b.w));
}
__device__ __forceinline__ int iclamp(int v, int lo, int hi) {
    return v < lo ? lo : (v > hi ? hi : v);
}

// LDS-only barrier: __syncthreads() compiles to s_waitcnt vmcnt(0) lgkmcnt(0)
// + s_barrier, draining our cross-step global prefetch. We only need LDS
// ordering here, so wait lgkmcnt(0) only and let VMEM stay in flight.
#define LDS_BARRIER() asm volatile("s_waitcnt lgkmcnt(0)\n\ts_barrier" ::: "memory")

// (512,2): CUDA-style min-blocks semantics on this compiler -> 2 blocks/CU,
// 4 waves/SIMD, 128-VGPR cap. (512,4) capped at 64 VGPR and spilled (r7/r8).
__global__ __launch_bounds__(512, 2)
void fused_nms_k(const float4* __restrict__ x4, float4* __restrict__ o4) {
    // double-buffered staging of per-plane W-max rows: 2 * 12 * 128 * 16B = 48 KB
    __shared__ float4 buf[2][ROWS * W4];

    const int tid = threadIdx.x;
    const int w4  = tid & (W4 - 1);              // 0..127
    const int hr  = tid >> 7;                    // 0..3
    // XCD swizzle: band = blockIdx&7 -> h-band of 64 rows stays on one XCD's L2
    const int b    = blockIdx.x;
    const int band = b & 7;
    const int rest = b >> 3;                     // 0..63
    const int ht   = band * 16 + (rest & 15);    // 0..127
    const int dc   = rest >> 4;                  // 0..3
    const int h0   = ht * TH;
    const int d0   = dc * DC;

    const int colm = w4 ? w4 - 1 : 0;
    const int colp = (w4 < W4 - 1) ? w4 + 1 : W4 - 1;

    // 9 per-thread element offsets within a plane (row + clamped col folded).
    int off[9];
#pragma unroll
    for (int k = 0; k < 3; ++k) {
        int gh = iclamp(h0 - RAD + hr + 4 * k, 0, Hh - 1);
        off[3 * k]     = gh * W4 + colm;
        off[3 * k + 1] = gh * W4 + w4;
        off[3 * k + 2] = gh * W4 + colp;
    }
    const int outrow = (h0 + hr) * W4 + w4;

    // Slot ring: R[t % 8] holds H-max of plane t, overwritten AFTER use.
    float4 R[8];
    float4 L[9];
    {   // preload plane for t=0
        const float4* pl = x4 + (size_t)iclamp(d0 - RAD, 0, Dd - 1) * PLANE4;
#pragma unroll
        for (int i = 0; i < 9; ++i) L[i] = pl[off[i]];
    }

    // One d-step. slot/par/emit compile-time at every call site.
    auto body = [&](int t, int slot, int par, bool emit) {
        float4* B = buf[par];
        // (1) W-max of the 3 staged rows — consumes L (vmcnt wait lands here)
        float4 o0, o1, o2;
        float4* op[3] = {&o0, &o1, &o2};
#pragma unroll
        for (int k = 0; k < 3; ++k) {
            float4 v0 = L[3 * k], v1 = L[3 * k + 1], v2 = L[3 * k + 2];
            float l3 = v0.w, l2 = fmaxf(v0.z, l3), l1 = fmaxf(v0.y, l2), l0 = fmaxf(v0.x, l1);
            float core = fmaxf(fmaxf(v1.x, v1.y), fmaxf(v1.z, v1.w));
            float r8 = v2.x, r9 = fmaxf(r8, v2.y), r10 = fmaxf(r9, v2.z), r11 = fmaxf(r10, v2.w);
            op[k]->x = fmaxf(l0, fmaxf(core, r8));
            op[k]->y = fmaxf(l1, fmaxf(core, r9));
            op[k]->z = fmaxf(l2, fmaxf(core, r10));
            op[k]->w = fmaxf(l3, fmaxf(core, r11));
        }
        // (2) L is dead — issue next plane's loads + this step's center NOW,
        //     BEFORE the barrier; the weak barrier lets them stay in flight
        //     for the whole ds_write/barrier/H-max phase (~full step).
        float4 cen;
        if (emit) cen = x4[(size_t)(d0 + t - 2 * RAD) * PLANE4 + outrow];
        if (t + 1 < STEPS) {
            const int gd = iclamp(d0 - RAD + t + 1, 0, Dd - 1);
            const float4* pl = x4 + (size_t)gd * PLANE4;
#pragma unroll
            for (int i = 0; i < 9; ++i) L[i] = pl[off[i]];
        }
        // (3) stage + LDS-only barrier (globals NOT drained)
        B[0 * 512 + tid] = o0;
        B[1 * 512 + tid] = o1;
        B[2 * 512 + tid] = o2;
        LDS_BARRIER();

        // (4) H-max over 9 staged rows at this thread's column
        const float4* Bb = B + hr * W4 + w4;
        float4 m = Bb[0];
#pragma unroll
        for (int i = 1; i < 9; ++i) m = f4max(m, Bb[i * W4]);

        // (5) emit: D-window-9 = max(8 ring slots, current m)
        if (emit) {
            float4 mm = m;
#pragma unroll
            for (int i = 0; i < 8; ++i) mm = f4max(mm, R[i]);
            nf4 q;
            q.x = (cen.x > THRESH_V && cen.x == mm.x) ? cen.x : 0.0f;
            q.y = (cen.y > THRESH_V && cen.y == mm.y) ? cen.y : 0.0f;
            q.z = (cen.z > THRESH_V && cen.z == mm.z) ? cen.z : 0.0f;
            q.w = (cen.w > THRESH_V && cen.w == mm.w) ? cen.w : 0.0f;
            __builtin_nontemporal_store(
                q, (nf4*)&o4[(size_t)(d0 + t - 2 * RAD) * PLANE4 + outrow]);
        }
        R[slot] = m;   // overwrite after use
    };

    // Prologue: fill ring with planes d0-4 .. d0+3 (clamped), no outputs.
#pragma unroll
    for (int t = 0; t < 8; ++t) body(t, t, t & 1, false);
    // Main: 16 emitting steps, unroll 8 so slot indices are static.
    for (int tb = 8; tb < STEPS; tb += 8) {
#pragma unroll
        for (int j = 0; j < 8; ++j) body(tb + j, j, j & 1, true);
    }
}

extern "C" void kernel_launch(void* const* d_in, const int* in_sizes, int n_in,
                              void* d_out, int out_size, void* d_ws, size_t ws_size,
                              hipStream_t stream) {
    const float4* x4 = (const float4*)d_in[0];
    float4* out4 = (float4*)d_out;
    (void)d_ws; (void)ws_size; (void)in_sizes; (void)n_in; (void)out_size;
    fused_nms_k<<<dim3(NBLK), dim3(512), 0, stream>>>(x4, out4);
}